// Round 3
// baseline (165.953 us; speedup 1.0000x reference)
//
#include <hip/hip_runtime.h>
#include <hip/hip_fp16.h>
#include <stdint.h>

// Problem constants (fixed by reference file)
#define TOKENS 65536   // T*B = 2048*32
#define D      128
#define NEXP   9       // MULTI_INFER_NUM + 1
#define MT     128     // tokens per tile (block)
#define MAXTILES (TOKENS / MT + NEXP)  // 521 upper bound on sum ceil(cnt_e/MT)
#define NHB    256     // hist blocks (TOKENS/256)

typedef _Float16 f16;
typedef _Float16 f16x8  __attribute__((ext_vector_type(8)));
typedef float    f32x16 __attribute__((ext_vector_type(16)));
typedef uint32_t u32;

// ---- workspace layout (int32 indices) ----
#define WI_TOKOFF  32            // [10]
#define WI_TILEOFF 48            // [10]
#define WI_HIST    128           // [256][9]
#define WI_BBASE   2432          // [256][9] absolute token base per (block,expert)
#define WI_PERM    4736          // [TOKENS]
#define WS_WF_OFF  ((4736 + TOKENS) * 4)   // f16 Wfrag[72][16384], 16B-aligned

__device__ __forceinline__ float sigm(float v) {
  return __builtin_amdgcn_rcpf(1.0f + __expf(-v));           // v_rcp_f32, not IEEE div
}
__device__ __forceinline__ float tanh_fast(float v) {
  return 1.0f - 2.0f * __builtin_amdgcn_rcpf(__expf(2.0f * v) + 1.0f);
}

// ---- fused prep: fragment-major f16 weights (blocks 0..287) + per-block expert hist (288..543) ----
// Wfrag[mat][c][kb][kh][n][i] = (f16) Ws[mat][d = kb*16+kh*8+i][f = c*32+n]
__global__ void k_prep(const float* __restrict__ Ws, const int* __restrict__ pos,
                       int* __restrict__ wsI, f16* __restrict__ Wf) {
  const int tid = threadIdx.x;
  if (blockIdx.x < 288) {
    const int mat = blockIdx.x >> 2;      // 0..71
    const int q   = blockIdx.x & 3;
    const float* src = Ws + (size_t)mat * (D * D);
    f16* dst = Wf + (size_t)mat * (D * D);
#pragma unroll
    for (int p = 0; p < 2; ++p) {
      int cc = q * 512 + p * 256 + tid;   // 16B chunk index 0..2047
      int n  = cc & 31;
      int khh = (cc >> 5) & 1;
      int kb = (cc >> 6) & 7;
      int c  = cc >> 9;
      int f  = c * 32 + n;
      int d0 = kb * 16 + khh * 8;
      f16x8 w;
#pragma unroll
      for (int i = 0; i < 8; ++i) w[i] = (f16)src[(d0 + i) * D + f];
      *(f16x8*)(dst + cc * 8) = w;
    }
  } else {
    const int b = blockIdx.x - 288;
    __shared__ int h[NEXP];
    if (tid < NEXP) h[tid] = 0;
    __syncthreads();
    int e = pos[b * 256 + tid]; e = e < 8 ? e : 8;
    atomicAdd(&h[e], 1);                  // LDS atomic — cheap
    __syncthreads();
    if (tid < NEXP) wsI[WI_HIST + b * NEXP + tid] = h[tid];
  }
}

// ---- one-block parallel scan: expert totals, token/tile offsets, per-block bases ----
__global__ void k_scan(int* __restrict__ wsI) {
  const int tid = threadIdx.x;            // 256 threads, tid == hist-block index
  const int lane = tid & 63, w = tid >> 6;
  __shared__ int wsum[4];
  __shared__ int totalsS[NEXP];
  __shared__ int tokoffS[NEXP + 1];
  int rel[NEXP];
  int myh[NEXP];
#pragma unroll
  for (int e = 0; e < NEXP; ++e) myh[e] = wsI[WI_HIST + tid * NEXP + e];

  for (int e = 0; e < NEXP; ++e) {
    int v = myh[e];
    int x = v;
#pragma unroll
    for (int off = 1; off < 64; off <<= 1) {
      int y = __shfl_up(x, off);
      if (lane >= off) x += y;
    }
    if (lane == 63) wsum[w] = x;
    __syncthreads();
    int add = 0;
    for (int w2 = 0; w2 < w; ++w2) add += wsum[w2];
    int incl = x + add;
    rel[e] = incl - v;                    // exclusive prefix over hist blocks
    if (tid == 255) totalsS[e] = incl;
    __syncthreads();
  }
  if (tid == 0) {
    int tok = 0, tile = 0;
    wsI[WI_TOKOFF] = 0; wsI[WI_TILEOFF] = 0; tokoffS[0] = 0;
    for (int e = 0; e < NEXP; ++e) {
      int cnt = totalsS[e];
      tok += cnt; tile += (cnt + MT - 1) / MT;
      wsI[WI_TOKOFF + e + 1] = tok;  tokoffS[e + 1] = tok;
      wsI[WI_TILEOFF + e + 1] = tile;
    }
  }
  __syncthreads();
#pragma unroll
  for (int e = 0; e < NEXP; ++e)
    wsI[WI_BBASE + tid * NEXP + e] = tokoffS[e] + rel[e];
}

// ---- assignment: ballot rank within wave, LDS wave offsets, zero global atomics ----
__global__ void k_assign(const int* __restrict__ pos, int* __restrict__ wsI) {
  const int tid = threadIdx.x, b = blockIdx.x;
  const int lane = tid & 63, w = tid >> 6;
  int e = pos[b * 256 + tid]; e = e < 8 ? e : 8;
  __shared__ int waveCnt[4][NEXP];
  __shared__ int waveBase[4][NEXP];
  int myRank = 0;
#pragma unroll
  for (int ee = 0; ee < NEXP; ++ee) {
    unsigned long long m = __ballot(e == ee);
    if (e == ee) myRank = __popcll(m & ((1ull << lane) - 1ull));
    if (lane == 0) waveCnt[w][ee] = __popcll(m);
  }
  __syncthreads();
  if (tid < NEXP) {
    int s = 0;
#pragma unroll
    for (int w2 = 0; w2 < 4; ++w2) { waveBase[w2][tid] = s; s += waveCnt[w2][tid]; }
  }
  __syncthreads();
  int base = wsI[WI_BBASE + b * NEXP + e];
  wsI[WI_PERM + base + waveBase[w][e] + myRank] = b * 256 + tid;
}

// Register-pipeline helpers (static names, parity-stable: 4 stages per c-iteration)
#define PREFETCH_B(BUF, LL, CC, JJ)                                            \
  do {                                                                         \
    if ((LL) < 2) {                                                            \
      const f16* _p = We + ((LL) * 4 + (JJ)) * 147456 + (CC) * 4096 + vlane;   \
      _Pragma("unroll")                                                        \
      for (int _kb = 0; _kb < 8; ++_kb)                                        \
        BUF[_kb] = *(const f16x8*)(_p + _kb * 512);                            \
    }                                                                          \
  } while (0)

#define MFMA_GROUP(ACC, BUF)                                                   \
  do {                                                                         \
    f32x16 _a;                                                                 \
    _Pragma("unroll") for (int _i = 0; _i < 16; ++_i) _a[_i] = 0.0f;           \
    _Pragma("unroll") for (int _kb = 0; _kb < 8; ++_kb)                        \
      _a = __builtin_amdgcn_mfma_f32_32x32x16_f16(aF[_kb], BUF[_kb], _a, 0, 0, 0); \
    ACC = _a;                                                                  \
  } while (0)

// ---- fused main: both layers, 4 gates, gating. Rolled loops => ~5.6KB hot body (I-cache-resident) ----
__launch_bounds__(256, 2)
__global__ void k_main(const float* __restrict__ xin, const float* __restrict__ bsPtr,
                       const int* __restrict__ wsI, const f16* __restrict__ Wf,
                       float* __restrict__ outPtr) {
  __shared__ __attribute__((aligned(16))) f16 Ash[MT][136];   // 272B row stride
  __shared__ int s_tok[MT];

  const int tid = threadIdx.x;
  const int bid = blockIdx.x;
  const int ntiles = wsI[WI_TILEOFF + NEXP];
  if (bid >= ntiles) return;

  // tile -> (expert, token range)
  int e = 0, tileOffE = 0;
#pragma unroll
  for (int ee = 0; ee < NEXP; ee++) {
    int to = wsI[WI_TILEOFF + ee];
    if (to <= bid) { e = ee; tileOffE = to; }
  }
  const int tokStart = wsI[WI_TOKOFF + e] + (bid - tileOffE) * MT;
  const int tokEnd   = wsI[WI_TOKOFF + e + 1];
  const int rowsValid = min(MT, tokEnd - tokStart);

  // ---- stage A (layer-0 x) as f16 via perm gather; zero-fill invalid rows ----
  {
    int m = tid >> 1, h = tid & 1;
    bool valid = (m < rowsValid);
    int tok = 0;
    if (valid) tok = wsI[WI_PERM + tokStart + m];
    if (h == 0) s_tok[m] = valid ? tok : -1;
    const float4* src = (const float4*)(xin + (size_t)tok * D + h * 64);
    f16* drow = &Ash[m][h * 64];
#pragma unroll
    for (int i = 0; i < 8; i++) {
      float4 a = make_float4(0.f, 0.f, 0.f, 0.f), b2 = a;
      if (valid) { a = src[2 * i]; b2 = src[2 * i + 1]; }
      f16x8 wv;
      wv[0] = (f16)a.x;  wv[1] = (f16)a.y;  wv[2] = (f16)a.z;  wv[3] = (f16)a.w;
      wv[4] = (f16)b2.x; wv[5] = (f16)b2.y; wv[6] = (f16)b2.z; wv[7] = (f16)b2.w;
      *(f16x8*)&drow[i * 8] = wv;
    }
  }
  __syncthreads();   // the ONLY block-wide barrier

  const int lane = tid & 63;
  const int colN = lane & 31;       // MFMA n / C-col
  const int kh   = lane >> 5;       // K-half
  const int rowBase = (tid >> 6) * 32;
  const int vlane = kh * 256 + colN * 8;            // lane-invariant B-frag offset (f16 elems)
  const f16* We = Wf + (size_t)e * 16384;           // (l*4+j) stride = 9*16384 = 147456

  f16x8 aF[8];
  f16x8 b0[8], b1[8];
  f32x16 acc0, acc1, acc2, acc3;

  PREFETCH_B(b0, 0, 0, 0);

#pragma unroll 1
  for (int l = 0; l < 2; l++) {
    // A fragments (own wave's rows; l=1 reads follow this wave's l=0 epilogue ds_writes)
    {
      int mA = rowBase + colN;
#pragma unroll
      for (int kb = 0; kb < 8; kb++)
        aF[kb] = *(const f16x8*)&Ash[mA][kb * 16 + kh * 8];
    }
#pragma unroll 1
    for (int c = 0; c < 4; c++) {
      const int f = c * 32 + colN;
      float bias[4];
#pragma unroll
      for (int j = 0; j < 4; j++)
        bias[j] = bsPtr[((l * 4 + j) * NEXP + e) * D + f];

      const int ln = (c == 3) ? l + 1 : l;          // next stage (j=0) coords
      const int cn = (c + 1) & 3;

      PREFETCH_B(b1, l, c, 1);   MFMA_GROUP(acc0, b0);
      PREFETCH_B(b0, l, c, 2);   MFMA_GROUP(acc1, b1);
      PREFETCH_B(b1, l, c, 3);   MFMA_GROUP(acc2, b0);
      PREFETCH_B(b0, ln, cn, 0); MFMA_GROUP(acc3, b1);

      // ---- gating epilogue for this 32-col chunk ----
#pragma unroll
      for (int r = 0; r < 16; r++) {
        int m = rowBase + (r & 3) + 8 * (r >> 2) + 4 * kh;  // C/D row mapping (m74/m101)
        float sf = acc0[r] + bias[0];
        float lg = acc1[r] + bias[1];
        float lf = acc2[r] + bias[2];
        float of = acc3[r] + bias[3];
        float xv = (float)Ash[m][f];
        float nr = xv * sigm(sf) + tanh_fast(lg) * sigm(lf);
        float xn = tanh_fast(nr) * sigm(of);
        if (l == 0) {
          Ash[m][f] = (f16)xn;             // becomes layer-1 A (own wave's rows only)
        } else {
          int tok = s_tok[m];
          if (tok >= 0) outPtr[(size_t)tok * D + f] = xn;
        }
      }
    }
  }
}

extern "C" void kernel_launch(void* const* d_in, const int* in_sizes, int n_in,
                              void* d_out, int out_size, void* d_ws, size_t ws_size,
                              hipStream_t stream) {
  const int*   pos = (const int*)d_in[0];
  const float* x   = (const float*)d_in[1];
  const float* Ws  = (const float*)d_in[2];
  const float* bs  = (const float*)d_in[3];
  float* out = (float*)d_out;
  int* wsI = (int*)d_ws;
  f16* Wf = (f16*)((char*)d_ws + WS_WF_OFF);

  k_prep  <<<544, 256, 0, stream>>>(Ws, pos, wsI, Wf);  // weights + hist
  k_scan  <<<1, 256, 0, stream>>>(wsI);
  k_assign<<<NHB, 256, 0, stream>>>(pos, wsI);
  k_main  <<<MAXTILES, 256, 0, stream>>>(x, bs, wsI, Wf, out);
}

// Round 4
// 145.910 us; speedup vs baseline: 1.1374x; 1.1374x over previous
//
#include <hip/hip_runtime.h>
#include <hip/hip_fp16.h>
#include <stdint.h>

// Problem constants (fixed by reference file)
#define TOKENS 65536   // T*B = 2048*32
#define D      128
#define NEXP   9       // MULTI_INFER_NUM + 1
#define MT     64      // tokens per tile (block of 256 thr = 4 waves x 16 rows)
#define MAXTILES (TOKENS / MT + NEXP)  // 1033
#define NHB    256     // hist blocks (TOKENS/256)

typedef _Float16 f16;
typedef _Float16 f16x8  __attribute__((ext_vector_type(8)));
typedef float    f32x4  __attribute__((ext_vector_type(4)));
typedef uint32_t u32;

// ---- workspace layout (int32 indices) ----
#define WI_TOKOFF  32            // [10]
#define WI_TILEOFF 48            // [10]
#define WI_HIST    128           // [256][9]
#define WI_BBASE   2432          // [256][9]
#define WI_PERM    4736          // [TOKENS]
#define WS_WF_OFF  ((4736 + TOKENS) * 4)   // f16 Wfrag[72][16384], 16B-aligned

#define LOG2E  1.44269504f
// guaranteed-native activations (v_exp_f32 + v_rcp_f32 only)
__device__ __forceinline__ float sigm(float v) {
  return __builtin_amdgcn_rcpf(1.0f + __builtin_amdgcn_exp2f(-LOG2E * v));
}
__device__ __forceinline__ float tanh_fast(float v) {
  return 1.0f - 2.0f * __builtin_amdgcn_rcpf(__builtin_amdgcn_exp2f(2.0f * LOG2E * v) + 1.0f);
}

// ---- fused prep: fragment-major f16 weights for 16x16x32 (blocks 0..287) + hist (288..543) ----
// Wf[mat][c(8)][kb(4)][lane(64)][i(8)], lane = quad*16 + n:
//   element = Ws[mat][d = kb*32 + quad*8 + i][f = c*16 + n]
__global__ void k_prep(const float* __restrict__ Ws, const int* __restrict__ pos,
                       int* __restrict__ wsI, f16* __restrict__ Wf) {
  const int tid = threadIdx.x;
  if (blockIdx.x < 288) {
    const int mat = blockIdx.x >> 2;      // 0..71
    const int q   = blockIdx.x & 3;
    const float* src = Ws + (size_t)mat * (D * D);
    f16* dst = Wf + (size_t)mat * (D * D);
#pragma unroll
    for (int p = 0; p < 2; ++p) {
      int cc = q * 512 + p * 256 + tid;   // 16B chunk index 0..2047 = ((c*4+kb)*64 + lane)
      int ln = cc & 63;
      int kb = (cc >> 6) & 3;
      int c  = cc >> 8;
      int quad = ln >> 4, n = ln & 15;
      int f  = c * 16 + n;
      int d0 = kb * 32 + quad * 8;
      f16x8 w;
#pragma unroll
      for (int i = 0; i < 8; ++i) w[i] = (f16)src[(d0 + i) * D + f];
      *(f16x8*)(dst + cc * 8) = w;
    }
  } else {
    const int b = blockIdx.x - 288;
    __shared__ int h[NEXP];
    if (tid < NEXP) h[tid] = 0;
    __syncthreads();
    int e = pos[b * 256 + tid]; e = e < 8 ? e : 8;
    atomicAdd(&h[e], 1);
    __syncthreads();
    if (tid < NEXP) wsI[WI_HIST + b * NEXP + tid] = h[tid];
  }
}

// ---- one-block parallel scan ----
__global__ void k_scan(int* __restrict__ wsI) {
  const int tid = threadIdx.x;
  const int lane = tid & 63, w = tid >> 6;
  __shared__ int wsum[4];
  __shared__ int totalsS[NEXP];
  __shared__ int tokoffS[NEXP + 1];
  int rel[NEXP];
  int myh[NEXP];
#pragma unroll
  for (int e = 0; e < NEXP; ++e) myh[e] = wsI[WI_HIST + tid * NEXP + e];

  for (int e = 0; e < NEXP; ++e) {
    int v = myh[e];
    int x = v;
#pragma unroll
    for (int off = 1; off < 64; off <<= 1) {
      int y = __shfl_up(x, off);
      if (lane >= off) x += y;
    }
    if (lane == 63) wsum[w] = x;
    __syncthreads();
    int add = 0;
    for (int w2 = 0; w2 < w; ++w2) add += wsum[w2];
    int incl = x + add;
    rel[e] = incl - v;
    if (tid == 255) totalsS[e] = incl;
    __syncthreads();
  }
  if (tid == 0) {
    int tok = 0, tile = 0;
    wsI[WI_TOKOFF] = 0; wsI[WI_TILEOFF] = 0; tokoffS[0] = 0;
    for (int e = 0; e < NEXP; ++e) {
      int cnt = totalsS[e];
      tok += cnt; tile += (cnt + MT - 1) / MT;
      wsI[WI_TOKOFF + e + 1] = tok;  tokoffS[e + 1] = tok;
      wsI[WI_TILEOFF + e + 1] = tile;
    }
  }
  __syncthreads();
#pragma unroll
  for (int e = 0; e < NEXP; ++e)
    wsI[WI_BBASE + tid * NEXP + e] = tokoffS[e] + rel[e];
}

// ---- assignment: ballot rank, zero global atomics ----
__global__ void k_assign(const int* __restrict__ pos, int* __restrict__ wsI) {
  const int tid = threadIdx.x, b = blockIdx.x;
  const int lane = tid & 63, w = tid >> 6;
  int e = pos[b * 256 + tid]; e = e < 8 ? e : 8;
  __shared__ int waveCnt[4][NEXP];
  __shared__ int waveBase[4][NEXP];
  int myRank = 0;
#pragma unroll
  for (int ee = 0; ee < NEXP; ++ee) {
    unsigned long long m = __ballot(e == ee);
    if (e == ee) myRank = __popcll(m & ((1ull << lane) - 1ull));
    if (lane == 0) waveCnt[w][ee] = __popcll(m);
  }
  __syncthreads();
  if (tid < NEXP) {
    int s = 0;
#pragma unroll
    for (int w2 = 0; w2 < 4; ++w2) { waveBase[w2][tid] = s; s += waveCnt[w2][tid]; }
  }
  __syncthreads();
  int base = wsI[WI_BBASE + b * NEXP + e];
  wsI[WI_PERM + base + waveBase[w][e] + myRank] = b * 256 + tid;
}

// ---- fused main: 16x16x32 MFMA, 16 rows/wave => ~95 VGPR => 4 waves/SIMD ----
__launch_bounds__(256, 4)
__global__ void k_main(const float* __restrict__ xin, const float* __restrict__ bsPtr,
                       const int* __restrict__ wsI, const f16* __restrict__ Wf,
                       float* __restrict__ outPtr) {
  __shared__ __attribute__((aligned(16))) f16 Ash[MT][136];   // 64 x 272B
  __shared__ int s_tok[MT];

  const int tid = threadIdx.x;
  const int bid = blockIdx.x;
  const int ntiles = wsI[WI_TILEOFF + NEXP];
  if (bid >= ntiles) return;

  // tile -> (expert, token range)
  int e = 0, tileOffE = 0;
#pragma unroll
  for (int ee = 0; ee < NEXP; ee++) {
    int to = wsI[WI_TILEOFF + ee];
    if (to <= bid) { e = ee; tileOffE = to; }
  }
  const int tokStart = wsI[WI_TOKOFF + e] + (bid - tileOffE) * MT;
  const int tokEnd   = wsI[WI_TOKOFF + e + 1];
  const int rowsValid = min(MT, tokEnd - tokStart);

  // ---- stage A (64 rows) as f16 via perm gather; zero-fill invalid rows ----
  {
    int m = tid >> 2, h = tid & 3;          // thread covers cols h*32..h*32+31
    bool valid = (m < rowsValid);
    int tok = 0;
    if (valid) tok = wsI[WI_PERM + tokStart + m];
    if (h == 0) s_tok[m] = valid ? tok : -1;
    const float4* src = (const float4*)(xin + (size_t)tok * D + h * 32);
    f16* drow = &Ash[m][h * 32];
#pragma unroll
    for (int i = 0; i < 4; i++) {
      float4 a = make_float4(0.f, 0.f, 0.f, 0.f), b2 = a;
      if (valid) { a = src[2 * i]; b2 = src[2 * i + 1]; }
      f16x8 wv;
      wv[0] = (f16)a.x;  wv[1] = (f16)a.y;  wv[2] = (f16)a.z;  wv[3] = (f16)a.w;
      wv[4] = (f16)b2.x; wv[5] = (f16)b2.y; wv[6] = (f16)b2.z; wv[7] = (f16)b2.w;
      *(f16x8*)&drow[i * 8] = wv;
    }
  }
  __syncthreads();   // the ONLY block-wide barrier

  const int lane = tid & 63;
  const int n    = lane & 15;       // MFMA col
  const int quad = lane >> 4;       // k-quad / row-quad
  const int rowBase = (tid >> 6) * 16;          // wave owns 16 rows
  const int vlane = lane * 8;                   // B-frag lane offset (f16 elems)
  const f16* We = Wf + (size_t)e * 16384;       // mat stride = 9*16384 = 147456

  f16x8 aF[4];
  f16x8 b0[4], b1[4];
  f32x4 acc0, acc1, acc2, acc3;

  // B prefetch: stage (l,c,j) kb-fragments into BUF
#define PREFETCH_B(BUF, LL, CC, JJ)                                            \
  do {                                                                         \
    if ((LL) < 2) {                                                            \
      const f16* _p = We + ((LL) * 4 + (JJ)) * 147456 + (CC) * 2048 + vlane;   \
      _Pragma("unroll")                                                        \
      for (int _kb = 0; _kb < 4; ++_kb)                                        \
        BUF[_kb] = *(const f16x8*)(_p + _kb * 512);                            \
    }                                                                          \
  } while (0)

#define MFMA_GROUP(ACC, BUF)                                                   \
  do {                                                                         \
    f32x4 _a = {0.f, 0.f, 0.f, 0.f};                                           \
    _Pragma("unroll") for (int _kb = 0; _kb < 4; ++_kb)                        \
      _a = __builtin_amdgcn_mfma_f32_16x16x32_f16(aF[_kb], BUF[_kb], _a, 0, 0, 0); \
    ACC = _a;                                                                  \
  } while (0)

  PREFETCH_B(b0, 0, 0, 0);

#pragma unroll 1
  for (int l = 0; l < 2; l++) {
    // A fragments: A[m = lane&15][k = kb*32 + quad*8 + i]
    {
      int mA = rowBase + n;
#pragma unroll
      for (int kb = 0; kb < 4; kb++)
        aF[kb] = *(const f16x8*)&Ash[mA][kb * 32 + quad * 8];
    }
#pragma unroll 1
    for (int c = 0; c < 8; c++) {
      const int f = c * 16 + n;
      float bias[4];
#pragma unroll
      for (int j = 0; j < 4; j++)
        bias[j] = bsPtr[((l * 4 + j) * NEXP + e) * D + f];

      const int ln = (c == 7) ? l + 1 : l;          // next stage (j=0) coords
      const int cn = (c + 1) & 7;

      PREFETCH_B(b1, l, c, 1);   MFMA_GROUP(acc0, b0);
      PREFETCH_B(b0, l, c, 2);   MFMA_GROUP(acc1, b1);
      PREFETCH_B(b1, l, c, 3);   MFMA_GROUP(acc2, b0);
      PREFETCH_B(b0, ln, cn, 0); MFMA_GROUP(acc3, b1);

      // ---- gating epilogue: 4 rows per lane (C/D row = quad*4 + r) ----
#pragma unroll
      for (int r = 0; r < 4; r++) {
        int m = rowBase + quad * 4 + r;
        float sf = acc0[r] + bias[0];
        float lg = acc1[r] + bias[1];
        float lf = acc2[r] + bias[2];
        float of = acc3[r] + bias[3];
        float xv = (float)Ash[m][f];
        float nr = xv * sigm(sf) + tanh_fast(lg) * sigm(lf);
        float xn = tanh_fast(nr) * sigm(of);
        if (l == 0) {
          Ash[m][f] = (f16)xn;             // layer-1 A (own wave's rows only)
        } else {
          int tok = s_tok[m];
          if (tok >= 0) outPtr[(size_t)tok * D + f] = xn;
        }
      }
    }
  }
#undef PREFETCH_B
#undef MFMA_GROUP
}

extern "C" void kernel_launch(void* const* d_in, const int* in_sizes, int n_in,
                              void* d_out, int out_size, void* d_ws, size_t ws_size,
                              hipStream_t stream) {
  const int*   pos = (const int*)d_in[0];
  const float* x   = (const float*)d_in[1];
  const float* Ws  = (const float*)d_in[2];
  const float* bs  = (const float*)d_in[3];
  float* out = (float*)d_out;
  int* wsI = (int*)d_ws;
  f16* Wf = (f16*)((char*)d_ws + WS_WF_OFF);

  k_prep  <<<544, 256, 0, stream>>>(Ws, pos, wsI, Wf);
  k_scan  <<<1, 256, 0, stream>>>(wsI);
  k_assign<<<NHB, 256, 0, stream>>>(pos, wsI);
  k_main  <<<MAXTILES, 256, 0, stream>>>(x, bs, wsI, Wf, out);
}

// Round 5
// 133.672 us; speedup vs baseline: 1.2415x; 1.0915x over previous
//
#include <hip/hip_runtime.h>
#include <hip/hip_fp16.h>
#include <stdint.h>

// Problem constants (fixed by reference file)
#define TOKENS 65536   // T*B = 2048*32
#define D      128
#define NEXP   9       // MULTI_INFER_NUM + 1
#define MT     32      // tokens per tile; block = 4 waves, each 32 rows x 32 cols
#define MAXTILES (TOKENS / MT + NEXP)  // 2057
#define NHB    256     // hist blocks (TOKENS/256)

typedef _Float16 f16;
typedef _Float16 f16x8  __attribute__((ext_vector_type(8)));
typedef float    f32x4  __attribute__((ext_vector_type(4)));
typedef uint32_t u32;

// ---- workspace layout (int32 indices) ----
#define WI_TOKOFF  32            // [10]
#define WI_TILEOFF 48            // [10]
#define WI_HIST    128           // [256][9]
#define WI_BBASE   2432          // [256][9]
#define WI_PERM    4736          // [TOKENS]
#define WS_WF_OFF  ((4736 + TOKENS) * 4)   // f16 Wfrag[72][16384], 16B-aligned

#define LOG2E  1.44269504f
// guaranteed-native activations (v_exp_f32 + v_rcp_f32 only)
__device__ __forceinline__ float sigm(float v) {
  return __builtin_amdgcn_rcpf(1.0f + __builtin_amdgcn_exp2f(-LOG2E * v));
}
__device__ __forceinline__ float tanh_fast(float v) {
  return 1.0f - 2.0f * __builtin_amdgcn_rcpf(__builtin_amdgcn_exp2f(2.0f * LOG2E * v) + 1.0f);
}

// ---- fused prep: fragment-major f16 weights for 16x16x32 (blocks 0..287) + hist (288..543) ----
// Wf[mat][c(8)][kb(4)][lane(64)][i(8)], lane = quad*16 + n:
//   element = Ws[mat][d = kb*32 + quad*8 + i][f = c*16 + n]
__global__ void k_prep(const float* __restrict__ Ws, const int* __restrict__ pos,
                       int* __restrict__ wsI, f16* __restrict__ Wf) {
  const int tid = threadIdx.x;
  if (blockIdx.x < 288) {
    const int mat = blockIdx.x >> 2;      // 0..71
    const int q   = blockIdx.x & 3;
    const float* src = Ws + (size_t)mat * (D * D);
    f16* dst = Wf + (size_t)mat * (D * D);
#pragma unroll
    for (int p = 0; p < 2; ++p) {
      int cc = q * 512 + p * 256 + tid;   // 16B chunk index 0..2047 = ((c*4+kb)*64 + lane)
      int ln = cc & 63;
      int kb = (cc >> 6) & 3;
      int c  = cc >> 8;
      int quad = ln >> 4, n = ln & 15;
      int f  = c * 16 + n;
      int d0 = kb * 32 + quad * 8;
      f16x8 w;
#pragma unroll
      for (int i = 0; i < 8; ++i) w[i] = (f16)src[(d0 + i) * D + f];
      *(f16x8*)(dst + cc * 8) = w;
    }
  } else {
    const int b = blockIdx.x - 288;
    __shared__ int h[NEXP];
    if (tid < NEXP) h[tid] = 0;
    __syncthreads();
    int e = pos[b * 256 + tid]; e = e < 8 ? e : 8;
    atomicAdd(&h[e], 1);
    __syncthreads();
    if (tid < NEXP) wsI[WI_HIST + b * NEXP + tid] = h[tid];
  }
}

// ---- one-block parallel scan ----
__global__ void k_scan(int* __restrict__ wsI) {
  const int tid = threadIdx.x;
  const int lane = tid & 63, w = tid >> 6;
  __shared__ int wsum[4];
  __shared__ int totalsS[NEXP];
  __shared__ int tokoffS[NEXP + 1];
  int rel[NEXP];
  int myh[NEXP];
#pragma unroll
  for (int e = 0; e < NEXP; ++e) myh[e] = wsI[WI_HIST + tid * NEXP + e];

  for (int e = 0; e < NEXP; ++e) {
    int v = myh[e];
    int x = v;
#pragma unroll
    for (int off = 1; off < 64; off <<= 1) {
      int y = __shfl_up(x, off);
      if (lane >= off) x += y;
    }
    if (lane == 63) wsum[w] = x;
    __syncthreads();
    int add = 0;
    for (int w2 = 0; w2 < w; ++w2) add += wsum[w2];
    int incl = x + add;
    rel[e] = incl - v;
    if (tid == 255) totalsS[e] = incl;
    __syncthreads();
  }
  if (tid == 0) {
    int tok = 0, tile = 0;
    wsI[WI_TOKOFF] = 0; wsI[WI_TILEOFF] = 0; tokoffS[0] = 0;
    for (int e = 0; e < NEXP; ++e) {
      int cnt = totalsS[e];
      tok += cnt; tile += (cnt + MT - 1) / MT;
      wsI[WI_TOKOFF + e + 1] = tok;  tokoffS[e + 1] = tok;
      wsI[WI_TILEOFF + e + 1] = tile;
    }
  }
  __syncthreads();
#pragma unroll
  for (int e = 0; e < NEXP; ++e)
    wsI[WI_BBASE + tid * NEXP + e] = tokoffS[e] + rel[e];
}

// ---- assignment: ballot rank, zero global atomics ----
__global__ void k_assign(const int* __restrict__ pos, int* __restrict__ wsI) {
  const int tid = threadIdx.x, b = blockIdx.x;
  const int lane = tid & 63, w = tid >> 6;
  int e = pos[b * 256 + tid]; e = e < 8 ? e : 8;
  __shared__ int waveCnt[4][NEXP];
  __shared__ int waveBase[4][NEXP];
  int myRank = 0;
#pragma unroll
  for (int ee = 0; ee < NEXP; ++ee) {
    unsigned long long m = __ballot(e == ee);
    if (e == ee) myRank = __popcll(m & ((1ull << lane) - 1ull));
    if (lane == 0) waveCnt[w][ee] = __popcll(m);
  }
  __syncthreads();
  if (tid < NEXP) {
    int s = 0;
#pragma unroll
    for (int w2 = 0; w2 < 4; ++w2) { waveBase[w2][tid] = s; s += waveCnt[w2][tid]; }
  }
  __syncthreads();
  int base = wsI[WI_BBASE + b * NEXP + e];
  wsI[WI_PERM + base + waveBase[w][e] + myRank] = b * 256 + tid;
}

// ---- fused main: 16x16x32 MFMA; wave = 32 rows (2 subtiles) x 32 cols (2 chunks);
//      each B fragment feeds 2 MFMAs -> half the L1 B-traffic of R4 at same occupancy ----
__launch_bounds__(256, 4)
__global__ void k_main(const float* __restrict__ xin, const float* __restrict__ bsPtr,
                       const int* __restrict__ wsI, const f16* __restrict__ Wf,
                       float* __restrict__ outPtr) {
  __shared__ __attribute__((aligned(16))) f16 Ash[MT][136];   // 32 x 272B
  __shared__ int s_tok[MT];

  const int tid = threadIdx.x;
  const int bid = blockIdx.x;
  const int ntiles = wsI[WI_TILEOFF + NEXP];
  if (bid >= ntiles) return;

  // tile -> (expert, token range)
  int e = 0, tileOffE = 0;
#pragma unroll
  for (int ee = 0; ee < NEXP; ee++) {
    int to = wsI[WI_TILEOFF + ee];
    if (to <= bid) { e = ee; tileOffE = to; }
  }
  const int tokStart = wsI[WI_TOKOFF + e] + (bid - tileOffE) * MT;
  const int tokEnd   = wsI[WI_TOKOFF + e + 1];
  const int rowsValid = min(MT, tokEnd - tokStart);

  // ---- stage A (32 rows) as f16 via perm gather; zero-fill invalid rows ----
  {
    int m = tid >> 3, h = tid & 7;          // thread covers cols h*16..h*16+15
    bool valid = (m < rowsValid);
    int tok = 0;
    if (valid) tok = wsI[WI_PERM + tokStart + m];
    if (h == 0) s_tok[m] = valid ? tok : -1;
    const float4* src = (const float4*)(xin + (size_t)tok * D + h * 16);
    f16* drow = &Ash[m][h * 16];
#pragma unroll
    for (int i = 0; i < 2; i++) {
      float4 a = make_float4(0.f, 0.f, 0.f, 0.f), b2 = a;
      if (valid) { a = src[2 * i]; b2 = src[2 * i + 1]; }
      f16x8 wv;
      wv[0] = (f16)a.x;  wv[1] = (f16)a.y;  wv[2] = (f16)a.z;  wv[3] = (f16)a.w;
      wv[4] = (f16)b2.x; wv[5] = (f16)b2.y; wv[6] = (f16)b2.z; wv[7] = (f16)b2.w;
      *(f16x8*)&drow[i * 8] = wv;
    }
  }
  __syncthreads();   // barrier 1: Ash staged

  const int lane = tid & 63;
  const int n    = lane & 15;       // MFMA col
  const int quad = lane >> 4;       // k-quad / row-quad
  const int cBase = (tid >> 6) * 2; // wave's first 16-col chunk (col-split across waves)
  const int vlane = lane * 8;       // B-frag lane offset (f16 elems)
  const f16* We = Wf + (size_t)e * 16384;   // mat stride = 9*16384 = 147456

  f16x8 aF0[4], aF1[4];             // A fragments: rows 0-15 / 16-31, full K=128
  f16x8 b0[4], b1[4];
  f32x4 acc[4][2];                  // [gate][subtile]

#define LOAD_AF()                                                              \
  do {                                                                         \
    _Pragma("unroll")                                                          \
    for (int _kb = 0; _kb < 4; ++_kb) {                                        \
      aF0[_kb] = *(const f16x8*)&Ash[n][_kb * 32 + quad * 8];                  \
      aF1[_kb] = *(const f16x8*)&Ash[16 + n][_kb * 32 + quad * 8];             \
    }                                                                          \
  } while (0)

#define PREFETCH_B(BUF, LL, CC, JJ)                                            \
  do {                                                                         \
    if ((LL) < 2) {                                                            \
      const f16* _p = We + ((LL) * 4 + (JJ)) * 147456 + (CC) * 2048 + vlane;   \
      _Pragma("unroll")                                                        \
      for (int _kb = 0; _kb < 4; ++_kb)                                        \
        BUF[_kb] = *(const f16x8*)(_p + _kb * 512);                            \
    }                                                                          \
  } while (0)

#define MFMA2(G, BUF)                                                          \
  do {                                                                         \
    f32x4 _x = {0.f, 0.f, 0.f, 0.f}, _y = {0.f, 0.f, 0.f, 0.f};                \
    _Pragma("unroll")                                                          \
    for (int _kb = 0; _kb < 4; ++_kb) {                                        \
      _x = __builtin_amdgcn_mfma_f32_16x16x32_f16(aF0[_kb], BUF[_kb], _x, 0, 0, 0); \
      _y = __builtin_amdgcn_mfma_f32_16x16x32_f16(aF1[_kb], BUF[_kb], _y, 0, 0, 0); \
    }                                                                          \
    acc[G][0] = _x; acc[G][1] = _y;                                            \
  } while (0)

  PREFETCH_B(b0, 0, cBase, 0);
  LOAD_AF();
  __syncthreads();   // barrier 2: all waves' aF(l=0) loaded before any Ash overwrite

#pragma unroll 1
  for (int l = 0; l < 2; l++) {
#pragma unroll 1
    for (int ci = 0; ci < 2; ci++) {
      const int cc = cBase + ci;
      const int f = cc * 16 + n;
      float bias[4];
#pragma unroll
      for (int j = 0; j < 4; j++)
        bias[j] = bsPtr[((l * 4 + j) * NEXP + e) * D + f];

      const int ln = (ci == 1) ? l + 1 : l;       // next stage (j=0) coords
      const int cn = (ci == 1) ? cBase : cc + 1;

      PREFETCH_B(b1, l, cc, 1);  MFMA2(0, b0);
      PREFETCH_B(b0, l, cc, 2);  MFMA2(1, b1);
      PREFETCH_B(b1, l, cc, 3);  MFMA2(2, b0);
      PREFETCH_B(b0, ln, cn, 0); MFMA2(3, b1);

      // ---- gating epilogue: 2 subtiles x 4 rows per lane ----
#pragma unroll
      for (int s = 0; s < 2; s++) {
#pragma unroll
        for (int r = 0; r < 4; r++) {
          int m = s * 16 + quad * 4 + r;          // C/D row mapping (m89)
          float sf = acc[0][s][r] + bias[0];
          float lg = acc[1][s][r] + bias[1];
          float lf = acc[2][s][r] + bias[2];
          float of = acc[3][s][r] + bias[3];
          float xv = (float)Ash[m][f];
          float nr = xv * sigm(sf) + tanh_fast(lg) * sigm(lf);
          float xn = tanh_fast(nr) * sigm(of);
          if (l == 0) {
            Ash[m][f] = (f16)xn;                  // layer-1 input (this wave's 32 cols)
          } else {
            int tok = s_tok[m];
            if (tok >= 0) outPtr[(size_t)tok * D + f] = xn;
          }
        }
      }
    }
    if (l == 0) {
      __syncthreads();   // barrier 3: all waves' l=0 Ash writes done
      LOAD_AF();         // reload full-K A fragments for layer 1
    }
  }
#undef LOAD_AF
#undef PREFETCH_B
#undef MFMA2
}

extern "C" void kernel_launch(void* const* d_in, const int* in_sizes, int n_in,
                              void* d_out, int out_size, void* d_ws, size_t ws_size,
                              hipStream_t stream) {
  const int*   pos = (const int*)d_in[0];
  const float* x   = (const float*)d_in[1];
  const float* Ws  = (const float*)d_in[2];
  const float* bs  = (const float*)d_in[3];
  float* out = (float*)d_out;
  int* wsI = (int*)d_ws;
  f16* Wf = (f16*)((char*)d_ws + WS_WF_OFF);

  k_prep  <<<544, 256, 0, stream>>>(Ws, pos, wsI, Wf);
  k_scan  <<<1, 256, 0, stream>>>(wsI);
  k_assign<<<NHB, 256, 0, stream>>>(pos, wsI);
  k_main  <<<MAXTILES, 256, 0, stream>>>(x, bs, wsI, Wf, out);
}